// Round 2
// baseline (237.420 us; speedup 1.0000x reference)
//
#include <hip/hip_runtime.h>

// MLoss: masked box-MSE + face-BCE + background-BCE over [B=2048, N=2704, C=5].
// 221 MB read once; graded wall 228 us, reduce kernel 66 us @ 3.4 TB/s effective.
//
// R2: atomic-free two-stage reduction (atomics to one line were a 270 us wall).
// R3-R5: 82-84 us invariant to occupancy/VGPR/LDS/MLP/cache-residency probes.
// R6: shfl_up for neighbor conf + nontemporal x loads -> 66 us.
// R7: rocprof showed VGPR=28 -- the "batched" 8-load chunk was compiled into a
//     serialized load->use chain (28 regs can't hold 64 regs of payload), so
//     per-wave MLP was ~2 and the kernel is round-trip latency bound (VALUBusy
//     28%, HBM 21%, no tier saturated). Fix: explicit register double-buffer
//     across grid-stride chunks, sched_barrier(0) pinning each prefetch batch
//     ahead of the previous chunk's compute, TPC 4->2 so both buffers fit
//     under the 64-VGPR / 8-waves-per-SIMD cliff (launch_bounds(256,8));
//     finer chunks also cut tail imbalance (3.3->6.6 chunks/block).
// R8: resubmit of R7 -- the MI355X container failed (infra), no signal came
//     back. Source functionally identical to R7.

#define BLOCK 256
#define TPC 2                    // tiles (256 groups each) per chunk, unrolled
#define LOG_CLAMP -100.0f

typedef float nvec4 __attribute__((ext_vector_type(4)));

__device__ __forceinline__ float clogf(float v) {
    return fmaxf(logf(v), LOG_CLAMP);
}

// One chunk's worth of in-flight data. All indexing is compile-time (full
// unroll) so this lives in registers: 2*(4+4)+2+2 = ~20 VGPRs per buffer.
struct ChunkBuf {
    nvec4  x4[TPC];
    float4 y4[TPC];
    float  yc0[TPC];
    int    rr[TPC];
};

__device__ __forceinline__ void load_chunk(
    int c, int wv, int lane,
    const nvec4* __restrict__ gx4, const float4* __restrict__ gy4,
    const float* __restrict__ y, ChunkBuf& b)
{
    #pragma unroll
    for (int k = 0; k < TPC; ++k) {
        const int g  = (c * TPC + k) * 256 + wv * 64 + lane;
        const int e0 = g * 4;
        const int r  = e0 % 5;
        b.rr[k]  = r;
        b.x4[k]  = __builtin_nontemporal_load(&gx4[g]);  // x: read-once, no alloc
        b.y4[k]  = gy4[g];
        // Lane 0 has no in-wave neighbor for the previous group's conf.
        b.yc0[k] = (lane == 0 && r != 0) ? y[e0 - r] : 0.0f;
    }
}

__device__ __forceinline__ void compute_chunk(
    const ChunkBuf& b, int lane,
    float& s_sq, float& s_bce, float& s_bg, float& s_cnt)
{
    #pragma unroll
    for (int k = 0; k < TPC; ++k) {
        const int    r = b.rr[k];
        const nvec4  X = b.x4[k];
        const float4 Y = b.y4[k];

        // Conf element of the cell starting inside this group (if any):
        // jc = (5-r)%5 < 4 for r != 1.
        const int jc = (5 - r) % 5;
        const float tnext = (jc == 0) ? Y.x : (jc == 1) ? Y.y : (jc == 2) ? Y.z : Y.w;
        const float pconf = (jc == 0) ? X.x : (jc == 1) ? X.y : (jc == 2) ? X.z : X.w;
        const bool  has_conf = (r != 1);

        const float lp  = clogf(pconf);
        const float l1p = clogf(1.0f - pconf);
        const bool  mc  = tnext > 0.5f;
        s_bce += (has_conf && mc)  ? -(tnext * lp + (1.0f - tnext) * l1p) : 0.0f;
        s_bg  += (has_conf && !mc) ? -l1p : 0.0f;
        s_cnt += (has_conf && mc)  ? 1.0f : 0.0f;

        // Conf of the cell containing e0: component (4-r_recv)&3 of lane
        // l-1's Y. Sender (r_s) side: r_recv=(r_s+4)%5 -> comp:
        // r_s=0 -> Y.x, r_s=2 -> Y.w, r_s=3 -> Y.z, r_s=4 -> Y.y (r_s=1 unused).
        const float outv = (r == 0) ? Y.x : (r == 2) ? Y.w : (r == 3) ? Y.z : Y.y;
        float ycp = __shfl_up(outv, 1, 64);
        if (lane == 0) ycp = b.yc0[k];
        const float yc = (r == 0) ? Y.x : ycp;

        // Box MSE: element j has m=r+j; m==0/5 is a conf element (skip);
        // cell conf is yc for m<5, tnext for m>5.
        #define MLOSS_BOX(J, XJ, YJ) do {                                 \
            const int   m  = r + (J);                                     \
            const bool  ic = (m == 0) || (m == 5);                        \
            const float tj = (m >= 5) ? tnext : yc;                       \
            const float d  = (XJ) - (YJ);                                 \
            s_sq += (!ic && tj > 0.5f) ? d * d : 0.0f;                    \
        } while (0)
        MLOSS_BOX(0, X.x, Y.x);
        MLOSS_BOX(1, X.y, Y.y);
        MLOSS_BOX(2, X.z, Y.z);
        MLOSS_BOX(3, X.w, Y.w);
        #undef MLOSS_BOX
    }
}

// Stage 1: grid-stride over chunks, register-double-buffered: chunk c+stride's
// loads are issued (and pinned by sched_barrier) before chunk c's compute, so
// the wave always has a full batch of loads in flight during compute.
__global__ __launch_bounds__(BLOCK, 8) void mloss_reduce(
    const float* __restrict__ x, const float* __restrict__ y,
    float4* __restrict__ partials, int n_chunks)
{
    const int lane = threadIdx.x & 63;
    const int wv   = threadIdx.x >> 6;

    const nvec4*  gx4 = (const nvec4*)x;
    const float4* gy4 = (const float4*)y;

    float s_sq = 0.0f, s_bce = 0.0f, s_bg = 0.0f, s_cnt = 0.0f;

    int c = blockIdx.x;
    const int stride = gridDim.x;
    if (c < n_chunks) {
        ChunkBuf A, B;
        load_chunk(c, wv, lane, gx4, gy4, y, A);
        c += stride;
        while (true) {
            if (c >= n_chunks) {
                compute_chunk(A, lane, s_sq, s_bce, s_bg, s_cnt);
                break;
            }
            load_chunk(c, wv, lane, gx4, gy4, y, B);
            __builtin_amdgcn_sched_barrier(0);   // pin B's loads before A's compute
            compute_chunk(A, lane, s_sq, s_bce, s_bg, s_cnt);
            c += stride;

            if (c >= n_chunks) {
                compute_chunk(B, lane, s_sq, s_bce, s_bg, s_cnt);
                break;
            }
            load_chunk(c, wv, lane, gx4, gy4, y, A);
            __builtin_amdgcn_sched_barrier(0);   // pin A's loads before B's compute
            compute_chunk(B, lane, s_sq, s_bce, s_bg, s_cnt);
            c += stride;
        }
    }

    // ---- Wave-64 butterfly reduce, then cross-wave via LDS ----
    #pragma unroll
    for (int off = 32; off > 0; off >>= 1) {
        s_sq  += __shfl_down(s_sq,  off, 64);
        s_bce += __shfl_down(s_bce, off, 64);
        s_bg  += __shfl_down(s_bg,  off, 64);
        s_cnt += __shfl_down(s_cnt, off, 64);
    }
    __shared__ float4 r_part[BLOCK / 64];
    if (lane == 0) r_part[wv] = make_float4(s_sq, s_bce, s_bg, s_cnt);
    __syncthreads();
    if (threadIdx.x == 0) {
        float4 t0 = r_part[0];
        #pragma unroll
        for (int w = 1; w < BLOCK / 64; ++w) {
            t0.x += r_part[w].x; t0.y += r_part[w].y;
            t0.z += r_part[w].z; t0.w += r_part[w].w;
        }
        partials[blockIdx.x] = t0;
    }
}

// Stage 2: one block reduces per-block partials (double accumulation),
// mops up tail elements not covered by full chunks, computes the scalar.
#define FBLOCK 1024
__global__ __launch_bounds__(FBLOCK) void mloss_final(
    const float4* __restrict__ partials, int n_parts,
    const float* __restrict__ x, const float* __restrict__ y,
    float* __restrict__ out, long long elem_start, long long n_elems,
    long long n_cells)
{
    double s_sq = 0.0, s_bce = 0.0, s_bg = 0.0, s_cnt = 0.0;
    for (int i = threadIdx.x; i < n_parts; i += FBLOCK) {
        const float4 v = partials[i];
        s_sq += (double)v.x; s_bce += (double)v.y;
        s_bg += (double)v.z; s_cnt += (double)v.w;
    }

    #pragma unroll
    for (int off = 32; off > 0; off >>= 1) {
        s_sq  += __shfl_down(s_sq,  off, 64);
        s_bce += __shfl_down(s_bce, off, 64);
        s_bg  += __shfl_down(s_bg,  off, 64);
        s_cnt += __shfl_down(s_cnt, off, 64);
    }

    __shared__ double r[FBLOCK / 64][4];
    const int wave = threadIdx.x >> 6;
    const int lane = threadIdx.x & 63;
    if (lane == 0) { r[wave][0] = s_sq; r[wave][1] = s_bce; r[wave][2] = s_bg; r[wave][3] = s_cnt; }
    __syncthreads();

    if (threadIdx.x == 0) {
        double t_sq = 0.0, t_bce = 0.0, t_bg = 0.0, face = 0.0;
        #pragma unroll
        for (int w = 0; w < FBLOCK / 64; ++w) {
            t_sq += r[w][0]; t_bce += r[w][1]; t_bg += r[w][2]; face += r[w][3];
        }
        for (long long e = elem_start; e < n_elems; ++e) {
            const long long m  = e % 5;
            const float t_cell = y[e - m];
            const bool  mask   = t_cell > 0.5f;
            if (m == 0) {
                const float p   = x[e];
                const float lp  = clogf(p);
                const float l1p = clogf(1.0f - p);
                if (mask) { t_bce += (double)(-(t_cell * lp + (1.0f - t_cell) * l1p)); face += 1.0; }
                else      { t_bg  += (double)(-l1p); }
            } else if (mask) {
                const float d = x[e] - y[e];
                t_sq += (double)(d * d);
            }
        }
        const double bg    = (double)n_cells - face;
        const double scale = 1.0 + 1.0 / face;
        *out = (float)(scale * t_sq / (face * 4.0) + scale * t_bce / face + t_bg / bg);
    }
}

extern "C" void kernel_launch(void* const* d_in, const int* in_sizes, int n_in,
                              void* d_out, int out_size, void* d_ws, size_t ws_size,
                              hipStream_t stream) {
    const float* x = (const float*)d_in[0];
    const float* y = (const float*)d_in[1];
    float* out = (float*)d_out;
    float4* partials = (float4*)d_ws;

    const long long n_elems  = (long long)in_sizes[0];   // B*N*5
    const long long n_cells  = n_elems / 5;              // B*N
    const long long n_groups = n_elems / 4;              // float4 groups
    const long long n_tiles  = n_groups / 256;           // 27040 for ref shape
    const int       n_chunks = (int)(n_tiles / TPC);     // 13520 for ref shape
    const long long covered  = (long long)n_chunks * TPC * 256 * 4;

    const int NB = (n_chunks < 2048) ? (n_chunks > 0 ? n_chunks : 1) : 2048;

    if (n_chunks > 0)
        mloss_reduce<<<NB, BLOCK, 0, stream>>>(x, y, partials, n_chunks);
    mloss_final<<<1, FBLOCK, 0, stream>>>(partials, (n_chunks > 0) ? NB : 0,
                                          x, y, out, covered, n_elems, n_cells);
}

// Round 3
// 227.935 us; speedup vs baseline: 1.0416x; 1.0416x over previous
//
#include <hip/hip_runtime.h>

// MLoss: masked box-MSE + face-BCE + background-BCE over [B=2048, N=2704, C=5].
// 221 MB read once; reduce kernel R6 = 66 us @ 3.4 TB/s effective.
//
// R2: atomic-free two-stage reduction (atomics to one line were a 270 us wall).
// R3-R5: 82-84 us invariant to occupancy/VGPR/LDS/MLP/cache-residency probes.
// R6: shfl_up for neighbor conf + nontemporal x loads -> 66 us.
// R7/R8: register double-buffer + sched_barrier(0) pinning, but with
//     __launch_bounds__(256,8): the 64-VGPR cap forced the pinned payload to
//     SCRATCH (WRITE_SIZE 64KB -> 32MB = 64 B/thread spill, VGPR stuck at 32,
//     dur 66 -> 72 us). Occupancy rose 56->74% but the scratch round-trip ate
//     the gain. The pipeline-vs-launch_bounds conflict, not the pipeline
//     itself, was falsified.
// R9: identical pipeline, cap relaxed to __launch_bounds__(256,4) (128 VGPRs,
//     ~R6's native occupancy). Verification signal: WRITE_SIZE back to ~64KB,
//     VGPR ~64-100. Prediction: reduce 38-50 us if latency-bound theory holds;
//     flat ~65 us => loads-in-flight wasn't the limiter, pivot to y/L3 path.

#define BLOCK 256
#define TPC 2                    // tiles (256 groups each) per chunk, unrolled
#define LOG_CLAMP -100.0f

typedef float nvec4 __attribute__((ext_vector_type(4)));

__device__ __forceinline__ float clogf(float v) {
    return fmaxf(logf(v), LOG_CLAMP);
}

// One chunk's worth of in-flight data. All indexing is compile-time (full
// unroll) so this lives in registers: 2*(4+4)+2+2 = ~20 VGPRs per buffer.
struct ChunkBuf {
    nvec4  x4[TPC];
    float4 y4[TPC];
    float  yc0[TPC];
    int    rr[TPC];
};

__device__ __forceinline__ void load_chunk(
    int c, int wv, int lane,
    const nvec4* __restrict__ gx4, const float4* __restrict__ gy4,
    const float* __restrict__ y, ChunkBuf& b)
{
    #pragma unroll
    for (int k = 0; k < TPC; ++k) {
        const int g  = (c * TPC + k) * 256 + wv * 64 + lane;
        const int e0 = g * 4;
        const int r  = e0 % 5;
        b.rr[k]  = r;
        b.x4[k]  = __builtin_nontemporal_load(&gx4[g]);  // x: read-once, no alloc
        b.y4[k]  = gy4[g];
        // Lane 0 has no in-wave neighbor for the previous group's conf.
        b.yc0[k] = (lane == 0 && r != 0) ? y[e0 - r] : 0.0f;
    }
}

__device__ __forceinline__ void compute_chunk(
    const ChunkBuf& b, int lane,
    float& s_sq, float& s_bce, float& s_bg, float& s_cnt)
{
    #pragma unroll
    for (int k = 0; k < TPC; ++k) {
        const int    r = b.rr[k];
        const nvec4  X = b.x4[k];
        const float4 Y = b.y4[k];

        // Conf element of the cell starting inside this group (if any):
        // jc = (5-r)%5 < 4 for r != 1.
        const int jc = (5 - r) % 5;
        const float tnext = (jc == 0) ? Y.x : (jc == 1) ? Y.y : (jc == 2) ? Y.z : Y.w;
        const float pconf = (jc == 0) ? X.x : (jc == 1) ? X.y : (jc == 2) ? X.z : X.w;
        const bool  has_conf = (r != 1);

        const float lp  = clogf(pconf);
        const float l1p = clogf(1.0f - pconf);
        const bool  mc  = tnext > 0.5f;
        s_bce += (has_conf && mc)  ? -(tnext * lp + (1.0f - tnext) * l1p) : 0.0f;
        s_bg  += (has_conf && !mc) ? -l1p : 0.0f;
        s_cnt += (has_conf && mc)  ? 1.0f : 0.0f;

        // Conf of the cell containing e0: component (4-r_recv)&3 of lane
        // l-1's Y. Sender (r_s) side: r_recv=(r_s+4)%5 -> comp:
        // r_s=0 -> Y.x, r_s=2 -> Y.w, r_s=3 -> Y.z, r_s=4 -> Y.y (r_s=1 unused).
        const float outv = (r == 0) ? Y.x : (r == 2) ? Y.w : (r == 3) ? Y.z : Y.y;
        float ycp = __shfl_up(outv, 1, 64);
        if (lane == 0) ycp = b.yc0[k];
        const float yc = (r == 0) ? Y.x : ycp;

        // Box MSE: element j has m=r+j; m==0/5 is a conf element (skip);
        // cell conf is yc for m<5, tnext for m>5.
        #define MLOSS_BOX(J, XJ, YJ) do {                                 \
            const int   m  = r + (J);                                     \
            const bool  ic = (m == 0) || (m == 5);                        \
            const float tj = (m >= 5) ? tnext : yc;                       \
            const float d  = (XJ) - (YJ);                                 \
            s_sq += (!ic && tj > 0.5f) ? d * d : 0.0f;                    \
        } while (0)
        MLOSS_BOX(0, X.x, Y.x);
        MLOSS_BOX(1, X.y, Y.y);
        MLOSS_BOX(2, X.z, Y.z);
        MLOSS_BOX(3, X.w, Y.w);
        #undef MLOSS_BOX
    }
}

// Stage 1: grid-stride over chunks, register-double-buffered: chunk c+stride's
// loads are issued (and pinned by sched_barrier) before chunk c's compute, so
// the wave always has a full batch of loads in flight during compute.
__global__ __launch_bounds__(BLOCK, 4) void mloss_reduce(
    const float* __restrict__ x, const float* __restrict__ y,
    float4* __restrict__ partials, int n_chunks)
{
    const int lane = threadIdx.x & 63;
    const int wv   = threadIdx.x >> 6;

    const nvec4*  gx4 = (const nvec4*)x;
    const float4* gy4 = (const float4*)y;

    float s_sq = 0.0f, s_bce = 0.0f, s_bg = 0.0f, s_cnt = 0.0f;

    int c = blockIdx.x;
    const int stride = gridDim.x;
    if (c < n_chunks) {
        ChunkBuf A, B;
        load_chunk(c, wv, lane, gx4, gy4, y, A);
        c += stride;
        while (true) {
            if (c >= n_chunks) {
                compute_chunk(A, lane, s_sq, s_bce, s_bg, s_cnt);
                break;
            }
            load_chunk(c, wv, lane, gx4, gy4, y, B);
            __builtin_amdgcn_sched_barrier(0);   // pin B's loads before A's compute
            compute_chunk(A, lane, s_sq, s_bce, s_bg, s_cnt);
            c += stride;

            if (c >= n_chunks) {
                compute_chunk(B, lane, s_sq, s_bce, s_bg, s_cnt);
                break;
            }
            load_chunk(c, wv, lane, gx4, gy4, y, A);
            __builtin_amdgcn_sched_barrier(0);   // pin A's loads before B's compute
            compute_chunk(B, lane, s_sq, s_bce, s_bg, s_cnt);
            c += stride;
        }
    }

    // ---- Wave-64 butterfly reduce, then cross-wave via LDS ----
    #pragma unroll
    for (int off = 32; off > 0; off >>= 1) {
        s_sq  += __shfl_down(s_sq,  off, 64);
        s_bce += __shfl_down(s_bce, off, 64);
        s_bg  += __shfl_down(s_bg,  off, 64);
        s_cnt += __shfl_down(s_cnt, off, 64);
    }
    __shared__ float4 r_part[BLOCK / 64];
    if (lane == 0) r_part[wv] = make_float4(s_sq, s_bce, s_bg, s_cnt);
    __syncthreads();
    if (threadIdx.x == 0) {
        float4 t0 = r_part[0];
        #pragma unroll
        for (int w = 1; w < BLOCK / 64; ++w) {
            t0.x += r_part[w].x; t0.y += r_part[w].y;
            t0.z += r_part[w].z; t0.w += r_part[w].w;
        }
        partials[blockIdx.x] = t0;
    }
}

// Stage 2: one block reduces per-block partials (double accumulation),
// mops up tail elements not covered by full chunks, computes the scalar.
#define FBLOCK 1024
__global__ __launch_bounds__(FBLOCK) void mloss_final(
    const float4* __restrict__ partials, int n_parts,
    const float* __restrict__ x, const float* __restrict__ y,
    float* __restrict__ out, long long elem_start, long long n_elems,
    long long n_cells)
{
    double s_sq = 0.0, s_bce = 0.0, s_bg = 0.0, s_cnt = 0.0;
    for (int i = threadIdx.x; i < n_parts; i += FBLOCK) {
        const float4 v = partials[i];
        s_sq += (double)v.x; s_bce += (double)v.y;
        s_bg += (double)v.z; s_cnt += (double)v.w;
    }

    #pragma unroll
    for (int off = 32; off > 0; off >>= 1) {
        s_sq  += __shfl_down(s_sq,  off, 64);
        s_bce += __shfl_down(s_bce, off, 64);
        s_bg  += __shfl_down(s_bg,  off, 64);
        s_cnt += __shfl_down(s_cnt, off, 64);
    }

    __shared__ double r[FBLOCK / 64][4];
    const int wave = threadIdx.x >> 6;
    const int lane = threadIdx.x & 63;
    if (lane == 0) { r[wave][0] = s_sq; r[wave][1] = s_bce; r[wave][2] = s_bg; r[wave][3] = s_cnt; }
    __syncthreads();

    if (threadIdx.x == 0) {
        double t_sq = 0.0, t_bce = 0.0, t_bg = 0.0, face = 0.0;
        #pragma unroll
        for (int w = 0; w < FBLOCK / 64; ++w) {
            t_sq += r[w][0]; t_bce += r[w][1]; t_bg += r[w][2]; face += r[w][3];
        }
        for (long long e = elem_start; e < n_elems; ++e) {
            const long long m  = e % 5;
            const float t_cell = y[e - m];
            const bool  mask   = t_cell > 0.5f;
            if (m == 0) {
                const float p   = x[e];
                const float lp  = clogf(p);
                const float l1p = clogf(1.0f - p);
                if (mask) { t_bce += (double)(-(t_cell * lp + (1.0f - t_cell) * l1p)); face += 1.0; }
                else      { t_bg  += (double)(-l1p); }
            } else if (mask) {
                const float d = x[e] - y[e];
                t_sq += (double)(d * d);
            }
        }
        const double bg    = (double)n_cells - face;
        const double scale = 1.0 + 1.0 / face;
        *out = (float)(scale * t_sq / (face * 4.0) + scale * t_bce / face + t_bg / bg);
    }
}

extern "C" void kernel_launch(void* const* d_in, const int* in_sizes, int n_in,
                              void* d_out, int out_size, void* d_ws, size_t ws_size,
                              hipStream_t stream) {
    const float* x = (const float*)d_in[0];
    const float* y = (const float*)d_in[1];
    float* out = (float*)d_out;
    float4* partials = (float4*)d_ws;

    const long long n_elems  = (long long)in_sizes[0];   // B*N*5
    const long long n_cells  = n_elems / 5;              // B*N
    const long long n_groups = n_elems / 4;              // float4 groups
    const long long n_tiles  = n_groups / 256;           // 27040 for ref shape
    const int       n_chunks = (int)(n_tiles / TPC);     // 13520 for ref shape
    const long long covered  = (long long)n_chunks * TPC * 256 * 4;

    const int NB = (n_chunks < 2048) ? (n_chunks > 0 ? n_chunks : 1) : 2048;

    if (n_chunks > 0)
        mloss_reduce<<<NB, BLOCK, 0, stream>>>(x, y, partials, n_chunks);
    mloss_final<<<1, FBLOCK, 0, stream>>>(partials, (n_chunks > 0) ? NB : 0,
                                          x, y, out, covered, n_elems, n_cells);
}